// Round 6
// baseline (487.488 us; speedup 1.0000x reference)
//
#include <hip/hip_runtime.h>
#include <cmath>

typedef __bf16 bf16x8 __attribute__((ext_vector_type(8)));
typedef __bf16 bf16x4 __attribute__((ext_vector_type(4)));
typedef float  f32x4  __attribute__((ext_vector_type(4)));

static __device__ __forceinline__ f32x4 mfma16(bf16x8 a, bf16x8 b, f32x4 c) {
    return __builtin_amdgcn_mfma_f32_16x16x32_bf16(a, b, c, 0, 0, 0);
}

static __device__ __forceinline__ float fast_exp2(float x) {
#if __has_builtin(__builtin_amdgcn_exp2f)
    return __builtin_amdgcn_exp2f(x);
#else
    return exp2f(x);
#endif
}

static __device__ __forceinline__ bf16x8 cvt8(float4 a, float4 b) {
    bf16x8 r;
    r[0] = (__bf16)a.x; r[1] = (__bf16)a.y; r[2] = (__bf16)a.z; r[3] = (__bf16)a.w;
    r[4] = (__bf16)b.x; r[5] = (__bf16)b.y; r[6] = (__bf16)b.z; r[7] = (__bf16)b.w;
    return r;
}

// ---------------- workspace layout (bytes) ----------------
#define OFF_STATS 0
#define OFF_XNT   (4096 + 2u*1024*1024)       // 8 MB bf16 xnT[b][p][c]; reused as attnT
#define OFF_QKT   (OFF_XNT + 8u*1024*1024)    // 16 MB bf16 qkT[b][p][1024] (q|k)
#define OFF_V     (OFF_QKT + 16u*1024*1024)   // 8 MB bf16 v[b][c][p]
#define OFF_OP    (OFF_V + 8u*1024*1024)      // NCH*8 MB bf16 Opart[ch][b][p][c]
#define CHUNK_O   4194304u                    // bf16 elems per chunk (2*4096*512)
#define CHUNK_L   65536u                      // fp32 elems per chunk (2*8*4096)

// ---------------- GroupNorm stats ----------------
__global__ __launch_bounds__(256) void gn_stats(const float* __restrict__ x,
                                                float* __restrict__ stats) {
    int blk = blockIdx.x;            // 256 blocks: 64 (b,g) groups x 4 chunks
    int bg = blk >> 2, chunk = blk & 3;
    const float* base = x + (size_t)bg * 65536 + (size_t)chunk * 16384;
    float s = 0.f, ss = 0.f;
    for (int i = threadIdx.x; i < 4096; i += 256) {
        float4 v = ((const float4*)base)[i];
        s  += v.x + v.y + v.z + v.w;
        ss += v.x*v.x + v.y*v.y + v.z*v.z + v.w*v.w;
    }
    #pragma unroll
    for (int off = 1; off < 64; off <<= 1) {
        s  += __shfl_xor(s,  off);
        ss += __shfl_xor(ss, off);
    }
    __shared__ float red[8];
    int wave = threadIdx.x >> 6;
    if ((threadIdx.x & 63) == 0) { red[wave*2] = s; red[wave*2+1] = ss; }
    __syncthreads();
    if (threadIdx.x == 0) {
        float S  = red[0] + red[2] + red[4] + red[6];
        float SS = red[1] + red[3] + red[5] + red[7];
        atomicAdd(&stats[bg*2],     S);
        atomicAdd(&stats[bg*2 + 1], SS);
    }
}

// ---------------- GroupNorm apply + transpose -> xnT[b][p][c] bf16 ----------------
__global__ __launch_bounds__(256) void gn_apply(const float* __restrict__ x,
                                                const float* __restrict__ stats,
                                                const float* __restrict__ w,
                                                const float* __restrict__ bgn,
                                                __bf16* __restrict__ xnT) {
    int p0 = blockIdx.x * 64, c0 = blockIdx.y * 64, b = blockIdx.z;
    int tid = threadIdx.x, lane = tid & 63, wave = tid >> 6;
    __shared__ float t[64][69];
    #pragma unroll
    for (int i = 0; i < 16; ++i) {
        int cc = i * 4 + wave;
        int c  = c0 + cc;
        int g  = (b << 5) + (c >> 4);
        float mu  = stats[g*2] * (1.f/65536.f);
        float var = stats[g*2+1] * (1.f/65536.f) - mu*mu;
        float rstd = rsqrtf(var + 1e-5f);
        float val = x[((size_t)(b*512 + c) << 12) + p0 + lane];
        t[cc][lane] = (val - mu) * rstd * w[c] + bgn[c];
    }
    __syncthreads();
    #pragma unroll
    for (int i = 0; i < 16; ++i) {
        int pp = i * 4 + wave;
        xnT[((size_t)(b*4096 + p0 + pp) << 9) + c0 + lane] = (__bf16)t[lane][pp];
    }
}

// ---------------- qk-projection: 128x128 MFMA GEMM, fp32 weights inline-cvt ----------------
// C[M=4096][N=1024] = xnT(4096x512 bf16) * [wq;wk](1024x512 fp32)^T
// cols<512 get bias bq and scale by qscale; cols>=512 get bias bkv.
__global__ __launch_bounds__(256) void gemm_qk_kernel(
    const __bf16* __restrict__ A, const float* __restrict__ Wq,
    const float* __restrict__ Wk,
    const float* __restrict__ bq, const float* __restrict__ bk,
    float qscale, __bf16* __restrict__ out) {
    const int bz = blockIdx.z;
    A += (size_t)bz * 2097152;
    const int m0 = blockIdx.x * 128, n0 = blockIdx.y * 128;
    const int tid = threadIdx.x, lane = tid & 63, wave = tid >> 6;
    const int quad = lane >> 4, l16 = lane & 15;
    const int wm = (wave >> 1) * 64, wn = (wave & 1) * 64;
    const int K = 512;

    __shared__ __attribute__((aligned(16))) __bf16 lds_a[128][40];
    __shared__ __attribute__((aligned(16))) __bf16 lds_b[128][40];

    f32x4 acc[4][4];
    #pragma unroll
    for (int mt = 0; mt < 4; ++mt)
        #pragma unroll
        for (int nt = 0; nt < 4; ++nt)
            #pragma unroll
            for (int r = 0; r < 4; ++r) acc[mt][nt][r] = 0.f;

    const int row_s = tid >> 2;
    const int kc    = (tid & 3) << 3;

    const __bf16* Abase = A + (size_t)(m0 + row_s) * K + kc;
    const int br0 = n0 + row_s, br1 = br0 + 64;
    const float* B0 = (br0 < 512) ? (Wq + (size_t)br0 * K + kc) : (Wk + (size_t)(br0 - 512) * K + kc);
    const float* B1 = (br1 < 512) ? (Wq + (size_t)br1 * K + kc) : (Wk + (size_t)(br1 - 512) * K + kc);

    uint4 ra0, ra1;
    float4 f0a, f0b, f1a, f1b;
    ra0 = *(const uint4*)Abase;
    ra1 = *(const uint4*)(Abase + (size_t)64 * K);
    f0a = *(const float4*)B0;      f0b = *(const float4*)(B0 + 4);
    f1a = *(const float4*)B1;      f1b = *(const float4*)(B1 + 4);

    for (int kt = 0; kt < K; kt += 32) {
        *(uint4*)&lds_a[row_s][kc]       = ra0;
        *(uint4*)&lds_a[row_s + 64][kc]  = ra1;
        *(bf16x8*)&lds_b[row_s][kc]      = cvt8(f0a, f0b);
        *(bf16x8*)&lds_b[row_s + 64][kc] = cvt8(f1a, f1b);
        __syncthreads();
        if (kt + 32 < K) {
            ra0 = *(const uint4*)(Abase + kt + 32);
            ra1 = *(const uint4*)(Abase + kt + 32 + (size_t)64 * K);
            f0a = *(const float4*)(B0 + kt + 32); f0b = *(const float4*)(B0 + kt + 36);
            f1a = *(const float4*)(B1 + kt + 32); f1b = *(const float4*)(B1 + kt + 36);
        }
        bf16x8 af[4], bfr[4];
        #pragma unroll
        for (int mt = 0; mt < 4; ++mt)
            af[mt] = *(const bf16x8*)&lds_a[wm + mt*16 + l16][quad*8];
        #pragma unroll
        for (int nt = 0; nt < 4; ++nt)
            bfr[nt] = *(const bf16x8*)&lds_b[wn + nt*16 + l16][quad*8];
        #pragma unroll
        for (int mt = 0; mt < 4; ++mt)
            #pragma unroll
            for (int nt = 0; nt < 4; ++nt)
                acc[mt][nt] = mfma16(af[mt], bfr[nt], acc[mt][nt]);
        __syncthreads();
    }

    #pragma unroll
    for (int mt = 0; mt < 4; ++mt) {
        const int mrow = m0 + wm + mt*16 + quad*4;
        #pragma unroll
        for (int nt = 0; nt < 4; ++nt) {
            const int ncol = n0 + wn + nt*16 + l16;
            #pragma unroll
            for (int r = 0; r < 4; ++r) {
                const int m = mrow + r;
                float bval = (ncol < 512) ? bq[ncol] : bk[ncol - 512];
                float val = acc[mt][nt][r] + bval;
                if (ncol < 512) val *= qscale;
                out[(size_t)bz * 4194304 + (size_t)m * 1024 + ncol] = (__bf16)val;
            }
        }
    }
}

// ---------------- 64x128 GEMM: fp32 weight A (inline cvt) x bf16 B, bias-m, opt res ----------------
template<int OUT_F32, int HAS_RES>
__global__ __launch_bounds__(256) void gemm64_kernel(
    const float* __restrict__ A, const __bf16* __restrict__ B,
    const float* __restrict__ bias, const float* __restrict__ res,
    void* __restrict__ out,
    int N, int K, long long strideB, long long strideO) {
    const int bz = blockIdx.z;
    B += strideB * bz;
    const int m0 = blockIdx.x * 64, n0 = blockIdx.y * 128;
    const int tid = threadIdx.x, lane = tid & 63, wave = tid >> 6;
    const int quad = lane >> 4, l16 = lane & 15;
    const int wn = wave * 32;

    __shared__ __attribute__((aligned(16))) __bf16 lds_a[64][40];
    __shared__ __attribute__((aligned(16))) __bf16 lds_b[128][40];

    f32x4 acc[4][2];
    #pragma unroll
    for (int mt = 0; mt < 4; ++mt)
        #pragma unroll
        for (int nt = 0; nt < 2; ++nt)
            #pragma unroll
            for (int r = 0; r < 4; ++r) acc[mt][nt][r] = 0.f;

    const int row_s = tid >> 2;
    const int kc    = (tid & 3) << 3;

    const float*  Abase = A + (size_t)(m0 + row_s) * K + kc;
    const __bf16* Bbase = B + (size_t)(n0 + row_s) * K + kc;
    float4 fa, fb;
    uint4 rb0, rb1;
    fa  = *(const float4*)Abase;  fb = *(const float4*)(Abase + 4);
    rb0 = *(const uint4*)Bbase;
    rb1 = *(const uint4*)(Bbase + (size_t)64 * K);

    for (int kt = 0; kt < K; kt += 32) {
        *(bf16x8*)&lds_a[row_s][kc]     = cvt8(fa, fb);
        *(uint4*)&lds_b[row_s][kc]      = rb0;
        *(uint4*)&lds_b[row_s + 64][kc] = rb1;
        __syncthreads();
        if (kt + 32 < K) {
            fa  = *(const float4*)(Abase + kt + 32); fb = *(const float4*)(Abase + kt + 36);
            rb0 = *(const uint4*)(Bbase + kt + 32);
            rb1 = *(const uint4*)(Bbase + kt + 32 + (size_t)64 * K);
        }
        bf16x8 af[4], bfr[2];
        #pragma unroll
        for (int mt = 0; mt < 4; ++mt)
            af[mt] = *(const bf16x8*)&lds_a[mt*16 + l16][quad*8];
        #pragma unroll
        for (int nt = 0; nt < 2; ++nt)
            bfr[nt] = *(const bf16x8*)&lds_b[wn + nt*16 + l16][quad*8];
        #pragma unroll
        for (int mt = 0; mt < 4; ++mt)
            #pragma unroll
            for (int nt = 0; nt < 2; ++nt)
                acc[mt][nt] = mfma16(af[mt], bfr[nt], acc[mt][nt]);
        __syncthreads();
    }

    #pragma unroll
    for (int mt = 0; mt < 4; ++mt) {
        const int mrow = m0 + mt*16 + quad*4;
        #pragma unroll
        for (int nt = 0; nt < 2; ++nt) {
            const int ncol = n0 + wn + nt*16 + l16;
            #pragma unroll
            for (int r = 0; r < 4; ++r) {
                const int m = mrow + r;
                float val = acc[mt][nt][r] + bias[m];
                const size_t idx = (size_t)strideO * bz + (size_t)m * N + ncol;
                if constexpr (HAS_RES) val += res[idx];
                if constexpr (OUT_F32) ((float*)out)[idx] = val;
                else ((__bf16*)out)[idx] = (__bf16)val;
            }
        }
    }
}

// ---------------- flash attention v4: 36 KB LDS, 4 blocks/CU ----------------
// S^T trick (lane holds 4 consecutive keys -> b64 P writes in PV A-layout),
// ones-column row sums, no-max exp2 softmax, half-tile P buffer (kc-split).
// qkT: [b][p][1024] bf16 (q pre-scaled by 0.125*log2e); v: [b][c][p] bf16
template<int NCH>
__global__ __launch_bounds__(256, 4) void attn_kernel(const __bf16* __restrict__ qkT,
                                                      const __bf16* __restrict__ v,
                                                      __bf16* __restrict__ attnT,
                                                      __bf16* __restrict__ Opart,
                                                      float* __restrict__ Lpart) {
    const int b = blockIdx.y >> 3, h = blockIdx.y & 7;
    const int chunk = (NCH > 1) ? blockIdx.z : 0;
    const int NITER = 64 / NCH;
    const int kt0 = chunk * (4096 / NCH);
    const int tid = threadIdx.x;
    const int wave = tid >> 6, lane = tid & 63;
    const int quad = lane >> 4, l16 = lane & 15;
    const int qbase = blockIdx.x * 256 + wave * 64;   // 64 queries per wave

    const __bf16* qkTb = qkT + ((size_t)b << 22);
    const __bf16* vb   = v   + ((size_t)b << 21);

    __shared__ __attribute__((aligned(16))) __bf16 lds_k[64][64];   // [key][d] swizzled, 8 KB
    __shared__ __attribute__((aligned(16))) __bf16 lds_v[80][64];   // [d][key] swizzled + ones row, 10 KB
    __shared__ __attribute__((aligned(16))) __bf16 lds_p[4][64][36];// per-wave P half-tile, 18 KB

    bf16x8 aq[4][2];
    #pragma unroll
    for (int mt = 0; mt < 4; ++mt) {
        const __bf16* qrow = qkTb + (size_t)(qbase + mt*16 + l16) * 1024 + h*64 + quad*8;
        aq[mt][0] = *(const bf16x8*)qrow;
        aq[mt][1] = *(const bf16x8*)(qrow + 32);
    }
    f32x4 o[4][5];   // o[mt][4] accumulates row-sums l via ones-column
    #pragma unroll
    for (int mt = 0; mt < 4; ++mt)
        #pragma unroll
        for (int dt = 0; dt < 5; ++dt)
            #pragma unroll
            for (int r = 0; r < 4; ++r) o[mt][dt][r] = 0.f;
    const f32x4 kZero = {0.f, 0.f, 0.f, 0.f};

    const int srow = tid >> 2;
    const int sc   = tid & 3;
    const int sw0  = ( sc      ^ (srow & 7)) * 8;
    const int sw1  = ((sc + 4) ^ (srow & 7)) * 8;

    const __bf16* kg0 = qkTb + (size_t)srow * 1024 + 512 + h*64 + sc*8;
    const __bf16* vg0 = vb + ((size_t)(h*64 + srow) << 12) + sc*8;

    // ones row for the l-accumulating MFMA tile
    if (tid < 64) lds_v[64][tid] = (__bf16)1.0f;

    uint4 ck0, ck1, cv0, cv1;
    {
        const __bf16* kg = kg0 + (size_t)kt0 * 1024;
        const __bf16* vg = vg0 + kt0;
        ck0 = *(const uint4*)kg; ck1 = *(const uint4*)(kg + 32);
        cv0 = *(const uint4*)vg; cv1 = *(const uint4*)(vg + 32);
    }

    for (int it = 0; it < NITER; ++it) {
        *(uint4*)&lds_k[srow][sw0] = ck0;
        *(uint4*)&lds_k[srow][sw1] = ck1;
        *(uint4*)&lds_v[srow][sw0] = cv0;
        *(uint4*)&lds_v[srow][sw1] = cv1;
        __syncthreads();
        if (it + 1 < NITER) {
            const int kt = kt0 + (it + 1) * 64;
            const __bf16* kg = kg0 + (size_t)kt * 1024;
            const __bf16* vg = vg0 + kt;
            ck0 = *(const uint4*)kg; ck1 = *(const uint4*)(kg + 32);
            cv0 = *(const uint4*)vg; cv1 = *(const uint4*)(vg + 32);
        }

        #pragma unroll
        for (int kc = 0; kc < 2; ++kc) {
            // Sc^T = K.Q^T for 32 keys (2 nt-tiles), exp2, pack -> half P buffer
            #pragma unroll
            for (int ntl = 0; ntl < 2; ++ntl) {
                const int nt = kc*2 + ntl;
                const int kr = nt*16 + l16;
                bf16x8 bk0 = *(const bf16x8*)&lds_k[kr][( quad      ^ (l16 & 7)) * 8];
                bf16x8 bk1 = *(const bf16x8*)&lds_k[kr][((4 + quad) ^ (l16 & 7)) * 8];
                #pragma unroll
                for (int mt = 0; mt < 4; ++mt) {
                    f32x4 s = mfma16(bk1, aq[mt][1], mfma16(bk0, aq[mt][0], kZero));
                    f32x4 p;
                    #pragma unroll
                    for (int r = 0; r < 4; ++r) p[r] = fast_exp2(s[r]);
                    bf16x4 pb = __builtin_convertvector(p, bf16x4);
                    *(bf16x4*)&lds_p[wave][mt*16 + l16][ntl*16 + quad*4] = pb;
                }
            }
            // PV + ones-column l accumulation (per-wave region: no barrier)
            bf16x8 pa[4];
            #pragma unroll
            for (int mt = 0; mt < 4; ++mt) {
                bf16x4 plo = *(const bf16x4*)&lds_p[wave][mt*16 + l16][quad*8];
                bf16x4 phi = *(const bf16x4*)&lds_p[wave][mt*16 + l16][quad*8 + 4];
                pa[mt] = __builtin_shufflevector(plo, phi, 0, 1, 2, 3, 4, 5, 6, 7);
            }
            #pragma unroll
            for (int dt = 0; dt < 5; ++dt) {
                bf16x8 bv = *(const bf16x8*)&lds_v[dt*16 + l16][((kc*4 + quad) ^ (l16 & 7)) * 8];
                #pragma unroll
                for (int mt = 0; mt < 4; ++mt)
                    o[mt][dt] = mfma16(pa[mt], bv, o[mt][dt]);
            }
        }
        __syncthreads();
    }

    if constexpr (NCH > 1) {
        __bf16* Ob = Opart + (size_t)chunk * CHUNK_O;
        #pragma unroll
        for (int mt = 0; mt < 4; ++mt)
            #pragma unroll
            for (int dt = 0; dt < 4; ++dt)
                #pragma unroll
                for (int r = 0; r < 4; ++r) {
                    size_t row = (size_t)b * 4096 + qbase + mt*16 + quad*4 + r;
                    Ob[(row << 9) + (h << 6) + dt*16 + l16] = (__bf16)o[mt][dt][r];
                }
        if (l16 == 0) {
            #pragma unroll
            for (int mt = 0; mt < 4; ++mt)
                #pragma unroll
                for (int r = 0; r < 4; ++r) {
                    int p = qbase + mt*16 + quad*4 + r;
                    Lpart[(size_t)chunk * CHUNK_L + (size_t)((b*8 + h) << 12) + p] = o[mt][4][r];
                }
        }
    } else {
        #pragma unroll
        for (int mt = 0; mt < 4; ++mt) {
            float inv[4];
            #pragma unroll
            for (int r = 0; r < 4; ++r)
                inv[r] = 1.f / __shfl(o[mt][4][r], lane & 48);
            #pragma unroll
            for (int dt = 0; dt < 4; ++dt)
                #pragma unroll
                for (int r = 0; r < 4; ++r) {
                    size_t row = (size_t)b * 4096 + qbase + mt*16 + quad*4 + r;
                    attnT[(row << 9) + (h << 6) + dt*16 + l16] = (__bf16)(o[mt][dt][r] * inv[r]);
                }
        }
    }
}

// ---------------- combine split-K partials (bf16) -> attnT bf16 ----------------
template<int NCH>
__global__ __launch_bounds__(256) void attn_combine(const __bf16* __restrict__ Opart,
                                                    const float* __restrict__ Lpart,
                                                    __bf16* __restrict__ attnT) {
    int i = blockIdx.x * 256 + threadIdx.x;   // 1,048,576 threads, 4 channels each
    int c4 = i & 127;
    int p  = (i >> 7) & 4095;
    int b  = i >> 19;
    int h  = c4 >> 4;
    size_t lidx = (size_t)((b*8 + h) << 12) + p;
    float l = 0.f;
    #pragma unroll
    for (int ch = 0; ch < NCH; ++ch) l += Lpart[(size_t)ch * CHUNK_L + lidx];
    float inv = 1.f / l;
    size_t oi = ((size_t)(b*4096 + p) << 9) + c4*4;   // bf16 elem index
    float acc[4] = {0.f, 0.f, 0.f, 0.f};
    #pragma unroll
    for (int ch = 0; ch < NCH; ++ch) {
        bf16x4 ov = *(const bf16x4*)&Opart[(size_t)ch * CHUNK_O + oi];
        #pragma unroll
        for (int r = 0; r < 4; ++r) acc[r] += (float)ov[r];
    }
    bf16x4 rv;
    #pragma unroll
    for (int r = 0; r < 4; ++r) rv[r] = (__bf16)(acc[r] * inv);
    *(bf16x4*)&attnT[oi] = rv;
}

extern "C" void kernel_launch(void* const* d_in, const int* in_sizes, int n_in,
                              void* d_out, int out_size, void* d_ws, size_t ws_size,
                              hipStream_t stream) {
    const float* x   = (const float*)d_in[0];
    const float* gnw = (const float*)d_in[1];
    const float* gnb = (const float*)d_in[2];
    const float* wq  = (const float*)d_in[3];
    const float* bq  = (const float*)d_in[4];
    const float* wkv = (const float*)d_in[5];
    const float* bkv = (const float*)d_in[6];
    const float* wo  = (const float*)d_in[7];
    const float* bo  = (const float*)d_in[8];
    float* out = (float*)d_out;

    char* ws = (char*)d_ws;
    float*  stats  = (float*)(ws + OFF_STATS);
    __bf16* xnT    = (__bf16*)(ws + OFF_XNT);
    __bf16* qkT    = (__bf16*)(ws + OFF_QKT);
    __bf16* vv     = (__bf16*)(ws + OFF_V);
    __bf16* Opart  = (__bf16*)(ws + OFF_OP);
    __bf16* attnT  = xnT;   // xnT dead after v-projection; reuse

    const size_t need4 = (size_t)OFF_OP + 4u * (CHUNK_O * 2 + CHUNK_L * 4);
    const size_t need2 = (size_t)OFF_OP + 2u * (CHUNK_O * 2 + CHUNK_L * 4);
    const int nch = (ws_size >= need4) ? 4 : (ws_size >= need2 ? 2 : 1);
    float* Lpart = (float*)(ws + OFF_OP + (size_t)nch * CHUNK_O * 2);

    hipMemsetAsync(stats, 0, 512, stream);
    gn_stats<<<256, 256, 0, stream>>>(x, stats);
    gn_apply<<<dim3(64, 8, 2), 256, 0, stream>>>(x, stats, gnw, gnb, xnT);

    const long long S = 2097152LL;   // 4096*512
    // qkT[p][c2] = xnT * [wq;wk]^T ; q cols scaled by 0.125*log2(e) for exp2 softmax
    gemm_qk_kernel<<<dim3(32, 8, 2), 256, 0, stream>>>(
        xnT, wq, wkv, bq, bkv, 0.125f * 1.44269504f, qkT);
    // v[c][p] = wv * xn  (M=512, N=4096), wv = wkv rows 512..1023 (fp32 inline cvt)
    gemm64_kernel<0,0><<<dim3(8, 32, 2), 256, 0, stream>>>(
        wkv + 262144, xnT, bkv + 512, nullptr, vv, 4096, 512, S, S);

    if (nch == 4) {
        attn_kernel<4><<<dim3(16, 16, 4), 256, 0, stream>>>(qkT, vv, nullptr, Opart, Lpart);
        attn_combine<4><<<4096, 256, 0, stream>>>(Opart, Lpart, attnT);
    } else if (nch == 2) {
        attn_kernel<2><<<dim3(16, 16, 2), 256, 0, stream>>>(qkT, vv, nullptr, Opart, Lpart);
        attn_combine<2><<<4096, 256, 0, stream>>>(Opart, Lpart, attnT);
    } else {
        attn_kernel<1><<<dim3(16, 16, 1), 256, 0, stream>>>(qkT, vv, attnT, nullptr, nullptr);
    }

    // out[c][p] = wo * attnOut + bo + residual (fp32)
    gemm64_kernel<1,1><<<dim3(8, 32, 2), 256, 0, stream>>>(
        wo, attnT, bo, x, out, 4096, 512, S, S);
}

// Round 7
// 231.732 us; speedup vs baseline: 2.1037x; 2.1037x over previous
//
#include <hip/hip_runtime.h>
#include <cmath>

typedef __bf16 bf16x8 __attribute__((ext_vector_type(8)));
typedef __bf16 bf16x4 __attribute__((ext_vector_type(4)));
typedef float  f32x4  __attribute__((ext_vector_type(4)));

static __device__ __forceinline__ f32x4 mfma16(bf16x8 a, bf16x8 b, f32x4 c) {
    return __builtin_amdgcn_mfma_f32_16x16x32_bf16(a, b, c, 0, 0, 0);
}

static __device__ __forceinline__ float fast_exp2(float x) {
#if __has_builtin(__builtin_amdgcn_exp2f)
    return __builtin_amdgcn_exp2f(x);
#else
    return exp2f(x);
#endif
}

static __device__ __forceinline__ bf16x8 cvt8(float4 a, float4 b) {
    bf16x8 r;
    r[0] = (__bf16)a.x; r[1] = (__bf16)a.y; r[2] = (__bf16)a.z; r[3] = (__bf16)a.w;
    r[4] = (__bf16)b.x; r[5] = (__bf16)b.y; r[6] = (__bf16)b.z; r[7] = (__bf16)b.w;
    return r;
}

// ---------------- workspace layout (bytes) ----------------
#define OFF_STATS 0
#define OFF_XNT   (4096 + 2u*1024*1024)       // 8 MB bf16 xnT[b][p][c]; reused as attnT
#define OFF_QKT   (OFF_XNT + 8u*1024*1024)    // 16 MB bf16 qkT[b][p][1024] (q|k)
#define OFF_V     (OFF_QKT + 16u*1024*1024)   // 8 MB bf16 v[b][c][p]
#define OFF_OP    (OFF_V + 8u*1024*1024)      // NCH*8 MB bf16 Opart[ch][b][p][c]
#define CHUNK_O   4194304u                    // bf16 elems per chunk (2*4096*512)
#define CHUNK_L   65536u                      // fp32 elems per chunk (2*8*4096)

// ---------------- GroupNorm stats ----------------
__global__ __launch_bounds__(256) void gn_stats(const float* __restrict__ x,
                                                float* __restrict__ stats) {
    int blk = blockIdx.x;            // 256 blocks: 64 (b,g) groups x 4 chunks
    int bg = blk >> 2, chunk = blk & 3;
    const float* base = x + (size_t)bg * 65536 + (size_t)chunk * 16384;
    float s = 0.f, ss = 0.f;
    for (int i = threadIdx.x; i < 4096; i += 256) {
        float4 v = ((const float4*)base)[i];
        s  += v.x + v.y + v.z + v.w;
        ss += v.x*v.x + v.y*v.y + v.z*v.z + v.w*v.w;
    }
    #pragma unroll
    for (int off = 1; off < 64; off <<= 1) {
        s  += __shfl_xor(s,  off);
        ss += __shfl_xor(ss, off);
    }
    __shared__ float red[8];
    int wave = threadIdx.x >> 6;
    if ((threadIdx.x & 63) == 0) { red[wave*2] = s; red[wave*2+1] = ss; }
    __syncthreads();
    if (threadIdx.x == 0) {
        float S  = red[0] + red[2] + red[4] + red[6];
        float SS = red[1] + red[3] + red[5] + red[7];
        atomicAdd(&stats[bg*2],     S);
        atomicAdd(&stats[bg*2 + 1], SS);
    }
}

// ---------------- GroupNorm apply + transpose -> xnT[b][p][c] bf16 ----------------
__global__ __launch_bounds__(256) void gn_apply(const float* __restrict__ x,
                                                const float* __restrict__ stats,
                                                const float* __restrict__ w,
                                                const float* __restrict__ bgn,
                                                __bf16* __restrict__ xnT) {
    int p0 = blockIdx.x * 64, c0 = blockIdx.y * 64, b = blockIdx.z;
    int tid = threadIdx.x, lane = tid & 63, wave = tid >> 6;
    __shared__ float t[64][69];
    #pragma unroll
    for (int i = 0; i < 16; ++i) {
        int cc = i * 4 + wave;
        int c  = c0 + cc;
        int g  = (b << 5) + (c >> 4);
        float mu  = stats[g*2] * (1.f/65536.f);
        float var = stats[g*2+1] * (1.f/65536.f) - mu*mu;
        float rstd = rsqrtf(var + 1e-5f);
        float val = x[((size_t)(b*512 + c) << 12) + p0 + lane];
        t[cc][lane] = (val - mu) * rstd * w[c] + bgn[c];
    }
    __syncthreads();
    #pragma unroll
    for (int i = 0; i < 16; ++i) {
        int pp = i * 4 + wave;
        xnT[((size_t)(b*4096 + p0 + pp) << 9) + c0 + lane] = (__bf16)t[lane][pp];
    }
}

// ---------------- qk-projection: 128x128 MFMA GEMM, fp32 weights inline-cvt ----------------
__global__ __launch_bounds__(256) void gemm_qk_kernel(
    const __bf16* __restrict__ A, const float* __restrict__ Wq,
    const float* __restrict__ Wk,
    const float* __restrict__ bq, const float* __restrict__ bk,
    float qscale, __bf16* __restrict__ out) {
    const int bz = blockIdx.z;
    A += (size_t)bz * 2097152;
    const int m0 = blockIdx.x * 128, n0 = blockIdx.y * 128;
    const int tid = threadIdx.x, lane = tid & 63, wave = tid >> 6;
    const int quad = lane >> 4, l16 = lane & 15;
    const int wm = (wave >> 1) * 64, wn = (wave & 1) * 64;
    const int K = 512;

    __shared__ __attribute__((aligned(16))) __bf16 lds_a[128][40];
    __shared__ __attribute__((aligned(16))) __bf16 lds_b[128][40];

    f32x4 acc[4][4];
    #pragma unroll
    for (int mt = 0; mt < 4; ++mt)
        #pragma unroll
        for (int nt = 0; nt < 4; ++nt)
            #pragma unroll
            for (int r = 0; r < 4; ++r) acc[mt][nt][r] = 0.f;

    const int row_s = tid >> 2;
    const int kc    = (tid & 3) << 3;

    const __bf16* Abase = A + (size_t)(m0 + row_s) * K + kc;
    const int br0 = n0 + row_s, br1 = br0 + 64;
    const float* B0 = (br0 < 512) ? (Wq + (size_t)br0 * K + kc) : (Wk + (size_t)(br0 - 512) * K + kc);
    const float* B1 = (br1 < 512) ? (Wq + (size_t)br1 * K + kc) : (Wk + (size_t)(br1 - 512) * K + kc);

    uint4 ra0, ra1;
    float4 f0a, f0b, f1a, f1b;
    ra0 = *(const uint4*)Abase;
    ra1 = *(const uint4*)(Abase + (size_t)64 * K);
    f0a = *(const float4*)B0;      f0b = *(const float4*)(B0 + 4);
    f1a = *(const float4*)B1;      f1b = *(const float4*)(B1 + 4);

    for (int kt = 0; kt < K; kt += 32) {
        *(uint4*)&lds_a[row_s][kc]       = ra0;
        *(uint4*)&lds_a[row_s + 64][kc]  = ra1;
        *(bf16x8*)&lds_b[row_s][kc]      = cvt8(f0a, f0b);
        *(bf16x8*)&lds_b[row_s + 64][kc] = cvt8(f1a, f1b);
        __syncthreads();
        if (kt + 32 < K) {
            ra0 = *(const uint4*)(Abase + kt + 32);
            ra1 = *(const uint4*)(Abase + kt + 32 + (size_t)64 * K);
            f0a = *(const float4*)(B0 + kt + 32); f0b = *(const float4*)(B0 + kt + 36);
            f1a = *(const float4*)(B1 + kt + 32); f1b = *(const float4*)(B1 + kt + 36);
        }
        bf16x8 af[4], bfr[4];
        #pragma unroll
        for (int mt = 0; mt < 4; ++mt)
            af[mt] = *(const bf16x8*)&lds_a[wm + mt*16 + l16][quad*8];
        #pragma unroll
        for (int nt = 0; nt < 4; ++nt)
            bfr[nt] = *(const bf16x8*)&lds_b[wn + nt*16 + l16][quad*8];
        #pragma unroll
        for (int mt = 0; mt < 4; ++mt)
            #pragma unroll
            for (int nt = 0; nt < 4; ++nt)
                acc[mt][nt] = mfma16(af[mt], bfr[nt], acc[mt][nt]);
        __syncthreads();
    }

    #pragma unroll
    for (int mt = 0; mt < 4; ++mt) {
        const int mrow = m0 + wm + mt*16 + quad*4;
        #pragma unroll
        for (int nt = 0; nt < 4; ++nt) {
            const int ncol = n0 + wn + nt*16 + l16;
            #pragma unroll
            for (int r = 0; r < 4; ++r) {
                const int m = mrow + r;
                float bval = (ncol < 512) ? bq[ncol] : bk[ncol - 512];
                float val = acc[mt][nt][r] + bval;
                if (ncol < 512) val *= qscale;
                out[(size_t)bz * 4194304 + (size_t)m * 1024 + ncol] = (__bf16)val;
            }
        }
    }
}

// ---------------- 64x128 GEMM: fp32 weight A (inline cvt) x bf16 B, bias-m, opt res ----------------
template<int OUT_F32, int HAS_RES>
__global__ __launch_bounds__(256) void gemm64_kernel(
    const float* __restrict__ A, const __bf16* __restrict__ B,
    const float* __restrict__ bias, const float* __restrict__ res,
    void* __restrict__ out,
    int N, int K, long long strideB, long long strideO) {
    const int bz = blockIdx.z;
    B += strideB * bz;
    const int m0 = blockIdx.x * 64, n0 = blockIdx.y * 128;
    const int tid = threadIdx.x, lane = tid & 63, wave = tid >> 6;
    const int quad = lane >> 4, l16 = lane & 15;
    const int wn = wave * 32;

    __shared__ __attribute__((aligned(16))) __bf16 lds_a[64][40];
    __shared__ __attribute__((aligned(16))) __bf16 lds_b[128][40];

    f32x4 acc[4][2];
    #pragma unroll
    for (int mt = 0; mt < 4; ++mt)
        #pragma unroll
        for (int nt = 0; nt < 2; ++nt)
            #pragma unroll
            for (int r = 0; r < 4; ++r) acc[mt][nt][r] = 0.f;

    const int row_s = tid >> 2;
    const int kc    = (tid & 3) << 3;

    const float*  Abase = A + (size_t)(m0 + row_s) * K + kc;
    const __bf16* Bbase = B + (size_t)(n0 + row_s) * K + kc;
    float4 fa, fb;
    uint4 rb0, rb1;
    fa  = *(const float4*)Abase;  fb = *(const float4*)(Abase + 4);
    rb0 = *(const uint4*)Bbase;
    rb1 = *(const uint4*)(Bbase + (size_t)64 * K);

    for (int kt = 0; kt < K; kt += 32) {
        *(bf16x8*)&lds_a[row_s][kc]     = cvt8(fa, fb);
        *(uint4*)&lds_b[row_s][kc]      = rb0;
        *(uint4*)&lds_b[row_s + 64][kc] = rb1;
        __syncthreads();
        if (kt + 32 < K) {
            fa  = *(const float4*)(Abase + kt + 32); fb = *(const float4*)(Abase + kt + 36);
            rb0 = *(const uint4*)(Bbase + kt + 32);
            rb1 = *(const uint4*)(Bbase + kt + 32 + (size_t)64 * K);
        }
        bf16x8 af[4], bfr[2];
        #pragma unroll
        for (int mt = 0; mt < 4; ++mt)
            af[mt] = *(const bf16x8*)&lds_a[mt*16 + l16][quad*8];
        #pragma unroll
        for (int nt = 0; nt < 2; ++nt)
            bfr[nt] = *(const bf16x8*)&lds_b[wn + nt*16 + l16][quad*8];
        #pragma unroll
        for (int mt = 0; mt < 4; ++mt)
            #pragma unroll
            for (int nt = 0; nt < 2; ++nt)
                acc[mt][nt] = mfma16(af[mt], bfr[nt], acc[mt][nt]);
        __syncthreads();
    }

    #pragma unroll
    for (int mt = 0; mt < 4; ++mt) {
        const int mrow = m0 + mt*16 + quad*4;
        #pragma unroll
        for (int nt = 0; nt < 2; ++nt) {
            const int ncol = n0 + wn + nt*16 + l16;
            #pragma unroll
            for (int r = 0; r < 4; ++r) {
                const int m = mrow + r;
                float val = acc[mt][nt][r] + bias[m];
                const size_t idx = (size_t)strideO * bz + (size_t)m * N + ncol;
                if constexpr (HAS_RES) val += res[idx];
                if constexpr (OUT_F32) ((float*)out)[idx] = val;
                else ((__bf16*)out)[idx] = (__bf16)val;
            }
        }
    }
}

// ---------------- flash attention v5: 36 KB LDS, 3 waves/SIMD (no spill) ----------------
// S^T trick (lane holds 4 consecutive keys -> b64 P writes in PV A-layout),
// ones-column row sums, no-max exp2 softmax, half-tile P buffer (kc-split).
// NOTE: launch_bounds min-waves MUST stay 3 — 4 caps unified VGPR+AGPR at 128
// and spills ~1.5 GB of scratch traffic (R6 post-mortem: WRITE_SIZE 38->966 MB).
template<int NCH>
__global__ __launch_bounds__(256, 3) void attn_kernel(const __bf16* __restrict__ qkT,
                                                      const __bf16* __restrict__ v,
                                                      __bf16* __restrict__ attnT,
                                                      __bf16* __restrict__ Opart,
                                                      float* __restrict__ Lpart) {
    const int b = blockIdx.y >> 3, h = blockIdx.y & 7;
    const int chunk = (NCH > 1) ? blockIdx.z : 0;
    const int NITER = 64 / NCH;
    const int kt0 = chunk * (4096 / NCH);
    const int tid = threadIdx.x;
    const int wave = tid >> 6, lane = tid & 63;
    const int quad = lane >> 4, l16 = lane & 15;
    const int qbase = blockIdx.x * 256 + wave * 64;   // 64 queries per wave

    const __bf16* qkTb = qkT + ((size_t)b << 22);
    const __bf16* vb   = v   + ((size_t)b << 21);

    __shared__ __attribute__((aligned(16))) __bf16 lds_k[64][64];   // [key][d] swizzled, 8 KB
    __shared__ __attribute__((aligned(16))) __bf16 lds_v[80][64];   // [d][key] swizzled + ones row, 10 KB
    __shared__ __attribute__((aligned(16))) __bf16 lds_p[4][64][36];// per-wave P half-tile, 18 KB

    bf16x8 aq[4][2];
    #pragma unroll
    for (int mt = 0; mt < 4; ++mt) {
        const __bf16* qrow = qkTb + (size_t)(qbase + mt*16 + l16) * 1024 + h*64 + quad*8;
        aq[mt][0] = *(const bf16x8*)qrow;
        aq[mt][1] = *(const bf16x8*)(qrow + 32);
    }
    f32x4 o[4][5];   // o[mt][4] accumulates row-sums l via ones-column
    #pragma unroll
    for (int mt = 0; mt < 4; ++mt)
        #pragma unroll
        for (int dt = 0; dt < 5; ++dt)
            #pragma unroll
            for (int r = 0; r < 4; ++r) o[mt][dt][r] = 0.f;
    const f32x4 kZero = {0.f, 0.f, 0.f, 0.f};

    const int srow = tid >> 2;
    const int sc   = tid & 3;
    const int sw0  = ( sc      ^ (srow & 7)) * 8;
    const int sw1  = ((sc + 4) ^ (srow & 7)) * 8;

    const __bf16* kg0 = qkTb + (size_t)srow * 1024 + 512 + h*64 + sc*8;
    const __bf16* vg0 = vb + ((size_t)(h*64 + srow) << 12) + sc*8;

    // ones row for the l-accumulating MFMA tile
    if (tid < 64) lds_v[64][tid] = (__bf16)1.0f;

    uint4 ck0, ck1, cv0, cv1;
    {
        const __bf16* kg = kg0 + (size_t)kt0 * 1024;
        const __bf16* vg = vg0 + kt0;
        ck0 = *(const uint4*)kg; ck1 = *(const uint4*)(kg + 32);
        cv0 = *(const uint4*)vg; cv1 = *(const uint4*)(vg + 32);
    }

    for (int it = 0; it < NITER; ++it) {
        *(uint4*)&lds_k[srow][sw0] = ck0;
        *(uint4*)&lds_k[srow][sw1] = ck1;
        *(uint4*)&lds_v[srow][sw0] = cv0;
        *(uint4*)&lds_v[srow][sw1] = cv1;
        __syncthreads();
        if (it + 1 < NITER) {
            const int kt = kt0 + (it + 1) * 64;
            const __bf16* kg = kg0 + (size_t)kt * 1024;
            const __bf16* vg = vg0 + kt;
            ck0 = *(const uint4*)kg; ck1 = *(const uint4*)(kg + 32);
            cv0 = *(const uint4*)vg; cv1 = *(const uint4*)(vg + 32);
        }

        #pragma unroll
        for (int kc = 0; kc < 2; ++kc) {
            // Sc^T = K.Q^T for 32 keys (2 nt-tiles), exp2, pack -> half P buffer
            #pragma unroll
            for (int ntl = 0; ntl < 2; ++ntl) {
                const int nt = kc*2 + ntl;
                const int kr = nt*16 + l16;
                bf16x8 bk0 = *(const bf16x8*)&lds_k[kr][( quad      ^ (l16 & 7)) * 8];
                bf16x8 bk1 = *(const bf16x8*)&lds_k[kr][((4 + quad) ^ (l16 & 7)) * 8];
                #pragma unroll
                for (int mt = 0; mt < 4; ++mt) {
                    f32x4 s = mfma16(bk1, aq[mt][1], mfma16(bk0, aq[mt][0], kZero));
                    f32x4 p;
                    #pragma unroll
                    for (int r = 0; r < 4; ++r) p[r] = fast_exp2(s[r]);
                    bf16x4 pb = __builtin_convertvector(p, bf16x4);
                    *(bf16x4*)&lds_p[wave][mt*16 + l16][ntl*16 + quad*4] = pb;
                }
            }
            // PV + ones-column l accumulation (per-wave region: no barrier)
            bf16x8 pa[4];
            #pragma unroll
            for (int mt = 0; mt < 4; ++mt) {
                bf16x4 plo = *(const bf16x4*)&lds_p[wave][mt*16 + l16][quad*8];
                bf16x4 phi = *(const bf16x4*)&lds_p[wave][mt*16 + l16][quad*8 + 4];
                pa[mt] = __builtin_shufflevector(plo, phi, 0, 1, 2, 3, 4, 5, 6, 7);
            }
            #pragma unroll
            for (int dt = 0; dt < 5; ++dt) {
                bf16x8 bv = *(const bf16x8*)&lds_v[dt*16 + l16][((kc*4 + quad) ^ (l16 & 7)) * 8];
                #pragma unroll
                for (int mt = 0; mt < 4; ++mt)
                    o[mt][dt] = mfma16(pa[mt], bv, o[mt][dt]);
            }
        }
        __syncthreads();
    }

    if constexpr (NCH > 1) {
        __bf16* Ob = Opart + (size_t)chunk * CHUNK_O;
        #pragma unroll
        for (int mt = 0; mt < 4; ++mt)
            #pragma unroll
            for (int dt = 0; dt < 4; ++dt)
                #pragma unroll
                for (int r = 0; r < 4; ++r) {
                    size_t row = (size_t)b * 4096 + qbase + mt*16 + quad*4 + r;
                    Ob[(row << 9) + (h << 6) + dt*16 + l16] = (__bf16)o[mt][dt][r];
                }
        if (l16 == 0) {
            #pragma unroll
            for (int mt = 0; mt < 4; ++mt)
                #pragma unroll
                for (int r = 0; r < 4; ++r) {
                    int p = qbase + mt*16 + quad*4 + r;
                    Lpart[(size_t)chunk * CHUNK_L + (size_t)((b*8 + h) << 12) + p] = o[mt][4][r];
                }
        }
    } else {
        #pragma unroll
        for (int mt = 0; mt < 4; ++mt) {
            float inv[4];
            #pragma unroll
            for (int r = 0; r < 4; ++r)
                inv[r] = 1.f / __shfl(o[mt][4][r], lane & 48);
            #pragma unroll
            for (int dt = 0; dt < 4; ++dt)
                #pragma unroll
                for (int r = 0; r < 4; ++r) {
                    size_t row = (size_t)b * 4096 + qbase + mt*16 + quad*4 + r;
                    attnT[(row << 9) + (h << 6) + dt*16 + l16] = (__bf16)(o[mt][dt][r] * inv[r]);
                }
        }
    }
}

// ---------------- combine split-K partials (bf16) -> attnT bf16 ----------------
template<int NCH>
__global__ __launch_bounds__(256) void attn_combine(const __bf16* __restrict__ Opart,
                                                    const float* __restrict__ Lpart,
                                                    __bf16* __restrict__ attnT) {
    int i = blockIdx.x * 256 + threadIdx.x;   // 1,048,576 threads, 4 channels each
    int c4 = i & 127;
    int p  = (i >> 7) & 4095;
    int b  = i >> 19;
    int h  = c4 >> 4;
    size_t lidx = (size_t)((b*8 + h) << 12) + p;
    float l = 0.f;
    #pragma unroll
    for (int ch = 0; ch < NCH; ++ch) l += Lpart[(size_t)ch * CHUNK_L + lidx];
    float inv = 1.f / l;
    size_t oi = ((size_t)(b*4096 + p) << 9) + c4*4;   // bf16 elem index
    float acc[4] = {0.f, 0.f, 0.f, 0.f};
    #pragma unroll
    for (int ch = 0; ch < NCH; ++ch) {
        bf16x4 ov = *(const bf16x4*)&Opart[(size_t)ch * CHUNK_O + oi];
        #pragma unroll
        for (int r = 0; r < 4; ++r) acc[r] += (float)ov[r];
    }
    bf16x4 rv;
    #pragma unroll
    for (int r = 0; r < 4; ++r) rv[r] = (__bf16)(acc[r] * inv);
    *(bf16x4*)&attnT[oi] = rv;
}

extern "C" void kernel_launch(void* const* d_in, const int* in_sizes, int n_in,
                              void* d_out, int out_size, void* d_ws, size_t ws_size,
                              hipStream_t stream) {
    const float* x   = (const float*)d_in[0];
    const float* gnw = (const float*)d_in[1];
    const float* gnb = (const float*)d_in[2];
    const float* wq  = (const float*)d_in[3];
    const float* bq  = (const float*)d_in[4];
    const float* wkv = (const float*)d_in[5];
    const float* bkv = (const float*)d_in[6];
    const float* wo  = (const float*)d_in[7];
    const float* bo  = (const float*)d_in[8];
    float* out = (float*)d_out;

    char* ws = (char*)d_ws;
    float*  stats  = (float*)(ws + OFF_STATS);
    __bf16* xnT    = (__bf16*)(ws + OFF_XNT);
    __bf16* qkT    = (__bf16*)(ws + OFF_QKT);
    __bf16* vv     = (__bf16*)(ws + OFF_V);
    __bf16* Opart  = (__bf16*)(ws + OFF_OP);
    __bf16* attnT  = xnT;   // xnT dead after v-projection; reuse

    const size_t need4 = (size_t)OFF_OP + 4u * (CHUNK_O * 2 + CHUNK_L * 4);
    const size_t need2 = (size_t)OFF_OP + 2u * (CHUNK_O * 2 + CHUNK_L * 4);
    const int nch = (ws_size >= need4) ? 4 : (ws_size >= need2 ? 2 : 1);
    float* Lpart = (float*)(ws + OFF_OP + (size_t)nch * CHUNK_O * 2);

    hipMemsetAsync(stats, 0, 512, stream);
    gn_stats<<<256, 256, 0, stream>>>(x, stats);
    gn_apply<<<dim3(64, 8, 2), 256, 0, stream>>>(x, stats, gnw, gnb, xnT);

    const long long S = 2097152LL;   // 4096*512
    // qkT[p][c2] = xnT * [wq;wk]^T ; q cols scaled by 0.125*log2(e) for exp2 softmax
    gemm_qk_kernel<<<dim3(32, 8, 2), 256, 0, stream>>>(
        xnT, wq, wkv, bq, bkv, 0.125f * 1.44269504f, qkT);
    // v[c][p] = wv * xn  (M=512, N=4096), wv = wkv rows 512..1023 (fp32 inline cvt)
    gemm64_kernel<0,0><<<dim3(8, 32, 2), 256, 0, stream>>>(
        wkv + 262144, xnT, bkv + 512, nullptr, vv, 4096, 512, S, S);

    if (nch == 4) {
        attn_kernel<4><<<dim3(16, 16, 4), 256, 0, stream>>>(qkT, vv, nullptr, Opart, Lpart);
        attn_combine<4><<<4096, 256, 0, stream>>>(Opart, Lpart, attnT);
    } else if (nch == 2) {
        attn_kernel<2><<<dim3(16, 16, 2), 256, 0, stream>>>(qkT, vv, nullptr, Opart, Lpart);
        attn_combine<2><<<4096, 256, 0, stream>>>(Opart, Lpart, attnT);
    } else {
        attn_kernel<1><<<dim3(16, 16, 1), 256, 0, stream>>>(qkT, vv, attnT, nullptr, nullptr);
    }

    // out[c][p] = wo * attnOut + bo + residual (fp32)
    gemm64_kernel<1,1><<<dim3(8, 32, 2), 256, 0, stream>>>(
        wo, attnT, bo, x, out, 4096, 512, S, S);
}